// Round 11
// baseline (74.630 us; speedup 1.0000x reference)
//
#include <hip/hip_runtime.h>
#include <cstdint>
#include <cstddef>

#define NB 8
#define NG 64
#define NP 50000
#define NPCH 32                 // p-chunks per row (2048 argmax blocks = 8/CU)
#define PCH 1563                // ceil(NP/NPCH)
#define NBLK4 49                // ceil((NP/4)/256) for the 4-wide streaming kernel

typedef float nfloat4 __attribute__((ext_vector_type(4)));  // native vec for nontemporal builtin

__device__ __forceinline__ void opaque(float& x) { asm volatile("" : "+v"(x)); }
__device__ __forceinline__ unsigned long long umax64(unsigned long long a, unsigned long long b) {
    return a > b ? a : b;
}

// ---------------------------------------------------------------------------
// Kernel B: row-oriented argmax partials, recomputing iou from pred.
// Grid (NPCH, 8 g-groups, NB); block = 8 g-rows x up-to-PCH preds.
// Inner loop keeps float/uint accumulators (3 ops per iou); u64 key built once
// at the end: (iou_bits<<32)|(~p) so u64-max == argmax w/ first-occurrence ties.
__global__ __launch_bounds__(256) void argmax_part(
    const float* __restrict__ pred,
    const float* __restrict__ gt,
    unsigned long long* __restrict__ part)
{
    __shared__ float s_gx0[8], s_gy0[8], s_gx1[8], s_gy1[8], s_ga[8];
    const int b  = blockIdx.z;
    const int gg = blockIdx.y;
    const int p0 = blockIdx.x * PCH;
    const int tid = threadIdx.x;

    if (tid < 8) {
        const float4 gb = reinterpret_cast<const float4*>(gt)[b * NG + gg * 8 + tid];
        float hw = 0.5f * gb.z, hh = 0.5f * gb.w;   // exact, FMA-safe
        float x0 = gb.x - hw, y0 = gb.y - hh;
        float x1 = gb.x + hw, y1 = gb.y + hh;
        float ga = (x1 - x0) * (y1 - y0);
        opaque(ga);
        s_gx0[tid] = x0; s_gy0[tid] = y0;
        s_gx1[tid] = x1; s_gy1[tid] = y1;
        s_ga[tid]  = ga;
    }
    __syncthreads();

    float        bv[8] = {-1.f,-1.f,-1.f,-1.f,-1.f,-1.f,-1.f,-1.f};
    unsigned int bp[8] = {0,0,0,0,0,0,0,0};

    for (int i = tid; i < PCH; i += 256) {
        const int p = p0 + i;
        if (p >= NP) break;
        const float4 pb = reinterpret_cast<const float4*>(pred)[(size_t)b * NP + p];
        float hw = 0.5f * pb.z, hh = 0.5f * pb.w;
        const float px0 = pb.x - hw, py0 = pb.y - hh;
        const float px1 = pb.x + hw, py1 = pb.y + hh;
        float pa = (px1 - px0) * (py1 - py0);
        opaque(pa);

        #pragma unroll
        for (int j = 0; j < 8; ++j) {
            // identical expression structure to the streaming kernel -> bitwise-equal iou
            float w = fmaxf(fminf(s_gx1[j], px1) - fmaxf(s_gx0[j], px0), 0.0f);
            float h = fmaxf(fminf(s_gy1[j], py1) - fmaxf(s_gy0[j], py0), 0.0f);
            float inter = w * h;
            opaque(inter);                           // numpy op order: (ga+pa)-inter
            float iou = inter / ((s_ga[j] + pa) - inter);  // IEEE div
            if (iou > bv[j]) { bv[j] = iou; bp[j] = (unsigned int)p; }  // static idx
        }
    }

    // block reduction: butterfly within wave, LDS across the 4 waves
    __shared__ unsigned long long s_part[8][4];
    const int lane = tid & 63;
    const int wv = tid >> 6;
    #pragma unroll
    for (int j = 0; j < 8; ++j) {
        unsigned long long k = 0;
        if (bv[j] >= 0.0f)
            k = ((unsigned long long)__float_as_uint(bv[j]) << 32) |
                (unsigned long long)(0xFFFFFFFFu - bp[j]);
        #pragma unroll
        for (int s = 1; s < 64; s <<= 1)
            k = umax64(k, __shfl_xor(k, s, 64));
        if (lane == 0) s_part[j][wv] = k;
    }
    __syncthreads();

    if (tid < 8) {
        unsigned long long r = umax64(umax64(s_part[tid][0], s_part[tid][1]),
                                      umax64(s_part[tid][2], s_part[tid][3]));
        part[((size_t)b * NG + (size_t)(gg * 8 + tid)) * NPCH + blockIdx.x] = r;
    }
}

// ---------------------------------------------------------------------------
// Kernel A: pure streaming — iou, pos (threshold | onehot), neg. 4 preds/thread,
// float4 nontemporal stores.
template<bool USE_AM>
__global__ __launch_bounds__(256) void iou_main(
    const float* __restrict__ pred,
    const float* __restrict__ gt,
    float* __restrict__ out_iou,
    float* __restrict__ out_pos,
    float* __restrict__ out_neg,
    const unsigned long long* __restrict__ part)
{
    __shared__ float s_gx0[NG], s_gy0[NG], s_gx1[NG], s_gy1[NG], s_ga[NG];
    __shared__ unsigned int s_am[NG];
    __shared__ unsigned long long s_red[NG][4];
    const int b = blockIdx.y;
    const int tid = threadIdx.x;

    if (tid < NG) {
        const float4 gb = reinterpret_cast<const float4*>(gt)[b * NG + tid];
        float hw = 0.5f * gb.z, hh = 0.5f * gb.w;   // exact, FMA-safe
        float x0 = gb.x - hw, y0 = gb.y - hh;
        float x1 = gb.x + hw, y1 = gb.y + hh;
        float ga = (x1 - x0) * (y1 - y0);
        opaque(ga);                                  // block FMA contraction into sums
        s_gx0[tid] = x0; s_gy0[tid] = y0;
        s_gx1[tid] = x1; s_gy1[tid] = y1;
        s_ga[tid]  = ga;
    }
    if (USE_AM) {                                    // parallel partial-key reduce
        const int gq = tid >> 2, q = tid & 3;
        const unsigned long long* pr = part + ((size_t)b * NG + gq) * NPCH + q * 8;
        unsigned long long r = pr[0];
        #pragma unroll
        for (int c = 1; c < 8; ++c) r = umax64(r, pr[c]);
        s_red[gq][q] = r;
    }
    __syncthreads();
    if (USE_AM) {
        if (tid < NG) {
            unsigned long long r = umax64(umax64(s_red[tid][0], s_red[tid][1]),
                                          umax64(s_red[tid][2], s_red[tid][3]));
            s_am[tid] = 0xFFFFFFFFu - (unsigned int)(r & 0xFFFFFFFFull);
        }
        __syncthreads();
    }

    const int pt = blockIdx.x * 256 + tid;
    if (pt >= NP / 4) return;                        // no barriers after this
    const int p = 4 * pt;

    float px0[4], py0[4], px1[4], py1[4], pa[4];
    #pragma unroll
    for (int k = 0; k < 4; ++k) {
        const float4 pb = reinterpret_cast<const float4*>(pred)[(size_t)b * NP + p + k];
        float hw = 0.5f * pb.z, hh = 0.5f * pb.w;
        px0[k] = pb.x - hw; py0[k] = pb.y - hh;
        px1[k] = pb.x + hw; py1[k] = pb.y + hh;
        float a = (px1[k] - px0[k]) * (py1[k] - py0[k]);
        opaque(a);
        pa[k] = a;
    }

    float maxv[4] = {0.0f, 0.0f, 0.0f, 0.0f};
    const size_t base = (size_t)b * NG * NP + (size_t)p;
    const unsigned int up = (unsigned int)p;

    #pragma unroll 2
    for (int g = 0; g < NG; ++g) {
        const float gx0 = s_gx0[g], gy0 = s_gy0[g];
        const float gx1 = s_gx1[g], gy1 = s_gy1[g];
        const float ga  = s_ga[g];

        float iou[4];
        #pragma unroll
        for (int k = 0; k < 4; ++k) {
            float w = fmaxf(fminf(gx1, px1[k]) - fmaxf(gx0, px0[k]), 0.0f);
            float h = fmaxf(fminf(gy1, py1[k]) - fmaxf(gy0, py0[k]), 0.0f);
            float inter = w * h;
            opaque(inter);                           // numpy op order: (ga+pa)-inter
            iou[k] = inter / ((ga + pa[k]) - inter); // IEEE div
            maxv[k] = fmaxf(maxv[k], iou[k]);
        }

        nfloat4 vi = { iou[0], iou[1], iou[2], iou[3] };
        __builtin_nontemporal_store(vi, reinterpret_cast<nfloat4*>(out_iou + base + (size_t)g * NP));

        nfloat4 vp;
        if (USE_AM) {
            const unsigned int am = s_am[g];
            vp.x = (iou[0] > 0.7f || am == up)      ? 1.0f : 0.0f;
            vp.y = (iou[1] > 0.7f || am == up + 1u) ? 1.0f : 0.0f;
            vp.z = (iou[2] > 0.7f || am == up + 2u) ? 1.0f : 0.0f;
            vp.w = (iou[3] > 0.7f || am == up + 3u) ? 1.0f : 0.0f;
        } else {
            vp.x = (iou[0] > 0.7f) ? 1.0f : 0.0f;
            vp.y = (iou[1] > 0.7f) ? 1.0f : 0.0f;
            vp.z = (iou[2] > 0.7f) ? 1.0f : 0.0f;
            vp.w = (iou[3] > 0.7f) ? 1.0f : 0.0f;
        }
        __builtin_nontemporal_store(vp, reinterpret_cast<nfloat4*>(out_pos + base + (size_t)g * NP));
    }

    nfloat4 vn;
    vn.x = (maxv[0] < 0.3f) ? 1.0f : 0.0f;
    vn.y = (maxv[1] < 0.3f) ? 1.0f : 0.0f;
    vn.z = (maxv[2] < 0.3f) ? 1.0f : 0.0f;
    vn.w = (maxv[3] < 0.3f) ? 1.0f : 0.0f;
    __builtin_nontemporal_store(vn, reinterpret_cast<nfloat4*>(out_neg + (size_t)b * NP + p));
}

// Fallback (ws too small): re-scan the iou row for argmax.
__global__ __launch_bounds__(256) void argmax_scan(
    const float* __restrict__ out_iou,
    float* __restrict__ out_pos)
{
    const int row = blockIdx.x;
    const float4* r4 = reinterpret_cast<const float4*>(out_iou + (size_t)row * NP);

    float bv = -1.0f;
    int   bi = 0x7fffffff;
    for (int c = threadIdx.x; c < NP / 4; c += 256) {
        float4 v = r4[c];
        int p = 4 * c;
        if (v.x > bv) { bv = v.x; bi = p; }
        if (v.y > bv) { bv = v.y; bi = p + 1; }
        if (v.z > bv) { bv = v.z; bi = p + 2; }
        if (v.w > bv) { bv = v.w; bi = p + 3; }
    }
    #pragma unroll
    for (int s = 1; s < 64; s <<= 1) {
        float ov = __shfl_xor(bv, s, 64);
        int   oi = __shfl_xor(bi, s, 64);
        if (ov > bv || (ov == bv && oi < bi)) { bv = ov; bi = oi; }
    }
    __shared__ float sv[4];
    __shared__ int   si[4];
    const int wid = threadIdx.x >> 6;
    if ((threadIdx.x & 63) == 0) { sv[wid] = bv; si[wid] = bi; }
    __syncthreads();
    if (threadIdx.x == 0) {
        for (int w = 1; w < 4; ++w)
            if (sv[w] > bv || (sv[w] == bv && si[w] < bi)) { bv = sv[w]; bi = si[w]; }
        out_pos[(size_t)row * NP + bi] = 1.0f;
    }
}

extern "C" void kernel_launch(void* const* d_in, const int* in_sizes, int n_in,
                              void* d_out, int out_size, void* d_ws, size_t ws_size,
                              hipStream_t stream) {
    const float* pred = (const float*)d_in[0];
    const float* gt   = (const float*)d_in[1];
    float* out_iou = (float*)d_out;
    float* out_pos = out_iou + (size_t)NB * NG * NP;
    float* out_neg = out_pos + (size_t)NB * NG * NP;

    const size_t part_bytes = (size_t)NB * NG * NPCH * sizeof(unsigned long long); // 128 KB
    dim3 gridA(NBLK4, NB);

    if (ws_size >= part_bytes) {
        unsigned long long* part = (unsigned long long*)d_ws;
        argmax_part<<<dim3(NPCH, NG / 8, NB), dim3(256), 0, stream>>>(pred, gt, part);
        iou_main<true><<<gridA, dim3(256), 0, stream>>>(pred, gt, out_iou, out_pos, out_neg, part);
    } else {
        iou_main<false><<<gridA, dim3(256), 0, stream>>>(pred, gt, out_iou, out_pos, out_neg, nullptr);
        argmax_scan<<<dim3(NB * NG), dim3(256), 0, stream>>>(out_iou, out_pos);
    }
}

// Round 12
// 55.006 us; speedup vs baseline: 1.3568x; 1.3568x over previous
//
#include <hip/hip_runtime.h>
#include <cstdint>
#include <cstddef>

#define NB 8
#define NG 64
#define NP 50000
#define NBLK 98                  // ceil((NP/2)/256) streaming blocks per batch
#define NSTREAM (NBLK * NB)      // 784 streaming blocks
#define NPCH 32                  // argmax p-chunks per row
#define PCH 1563                 // ceil(NP/NPCH); 32*1563 = 50016 >= NP
#define NAMAX (NPCH * (NG / 8) * NB)  // 2048 argmax blocks

__device__ __forceinline__ void opaque(float& x) { asm volatile("" : "+v"(x)); }
__device__ __forceinline__ unsigned long long umax64(unsigned long long a, unsigned long long b) {
    return a > b ? a : b;
}

// ---------------------------------------------------------------------------
// Fat kernel, block-role dispatch:
//   bid < NSTREAM           : streaming role — iou, pos(threshold), neg (proven R3 body)
//   bid >= NSTREAM (W_AM)   : argmax role — recompute iou rows, write u64 partials
// Roles are independent (both read only pred/gt) -> safe co-scheduling, no
// cross-block ordering assumed. Argmax VALU work hides in streaming's memory
// bubbles (streaming VALUBusy ~18%).
template<bool WITH_ARGMAX>
__global__ __launch_bounds__(256) void fused_main(
    const float* __restrict__ pred,
    const float* __restrict__ gt,
    float* __restrict__ out_iou,
    float* __restrict__ out_pos,
    float* __restrict__ out_neg,
    unsigned long long* __restrict__ part)
{
    const int bid = blockIdx.x;
    const int tid = threadIdx.x;

    if (!WITH_ARGMAX || bid < NSTREAM) {
        // ----------------- streaming role (R3-proven, bit-exact) -----------------
        __shared__ float s_gx0[NG], s_gy0[NG], s_gx1[NG], s_gy1[NG], s_ga[NG];
        const int b  = bid / NBLK;
        const int bx = bid % NBLK;

        if (tid < NG) {
            const float4 gb = reinterpret_cast<const float4*>(gt)[b * NG + tid];
            float hw = 0.5f * gb.z, hh = 0.5f * gb.w;   // exact, FMA-safe
            float x0 = gb.x - hw, y0 = gb.y - hh;
            float x1 = gb.x + hw, y1 = gb.y + hh;
            float ga = (x1 - x0) * (y1 - y0);
            opaque(ga);                                  // block FMA contraction
            s_gx0[tid] = x0; s_gy0[tid] = y0;
            s_gx1[tid] = x1; s_gy1[tid] = y1;
            s_ga[tid]  = ga;
        }
        __syncthreads();

        const int p = 2 * (bx * 256 + tid);
        if (p >= NP) return;                             // no barriers after this

        const float4 pb0 = reinterpret_cast<const float4*>(pred)[(size_t)b * NP + p];
        const float4 pb1 = reinterpret_cast<const float4*>(pred)[(size_t)b * NP + p + 1];

        float hw0 = 0.5f * pb0.z, hh0 = 0.5f * pb0.w;
        const float ax0 = pb0.x - hw0, ay0 = pb0.y - hh0;
        const float ax1 = pb0.x + hw0, ay1 = pb0.y + hh0;
        float pa0 = (ax1 - ax0) * (ay1 - ay0);
        opaque(pa0);

        float hw1 = 0.5f * pb1.z, hh1 = 0.5f * pb1.w;
        const float bx0 = pb1.x - hw1, by0 = pb1.y - hh1;
        const float bx1 = pb1.x + hw1, by1 = pb1.y + hh1;
        float pa1 = (bx1 - bx0) * (by1 - by0);
        opaque(pa1);

        float maxv0 = 0.0f, maxv1 = 0.0f;
        const size_t base = (size_t)b * NG * NP + (size_t)p;

        #pragma unroll 8
        for (int g = 0; g < NG; ++g) {
            const float gx0 = s_gx0[g], gy0 = s_gy0[g];
            const float gx1 = s_gx1[g], gy1 = s_gy1[g];
            const float ga  = s_ga[g];

            float w0 = fmaxf(fminf(gx1, ax1) - fmaxf(gx0, ax0), 0.0f);
            float h0 = fmaxf(fminf(gy1, ay1) - fmaxf(gy0, ay0), 0.0f);
            float inter0 = w0 * h0;
            opaque(inter0);                              // numpy op order: (ga+pa)-inter
            float iou0 = inter0 / ((ga + pa0) - inter0); // IEEE div

            float w1 = fmaxf(fminf(gx1, bx1) - fmaxf(gx0, bx0), 0.0f);
            float h1 = fmaxf(fminf(gy1, by1) - fmaxf(gy0, by0), 0.0f);
            float inter1 = w1 * h1;
            opaque(inter1);
            float iou1 = inter1 / ((ga + pa1) - inter1);

            float2 vi; vi.x = iou0; vi.y = iou1;
            *reinterpret_cast<float2*>(out_iou + base + (size_t)g * NP) = vi;

            float2 vp; vp.x = (iou0 > 0.7f) ? 1.0f : 0.0f;
                       vp.y = (iou1 > 0.7f) ? 1.0f : 0.0f;
            *reinterpret_cast<float2*>(out_pos + base + (size_t)g * NP) = vp;

            maxv0 = fmaxf(maxv0, iou0);
            maxv1 = fmaxf(maxv1, iou1);
        }

        float2 vn; vn.x = (maxv0 < 0.3f) ? 1.0f : 0.0f;
                   vn.y = (maxv1 < 0.3f) ? 1.0f : 0.0f;
        *reinterpret_cast<float2*>(out_neg + (size_t)b * NP + p) = vn;
    } else {
        // ----------------- argmax role (f32/u32 accumulators) -----------------
        __shared__ float a_gx0[8], a_gy0[8], a_gx1[8], a_gy1[8], a_ga[8];
        __shared__ unsigned long long s_part[8][4];

        const int a     = bid - NSTREAM;                 // 0..NAMAX-1
        const int chunk = a % NPCH;
        const int t2    = a / NPCH;
        const int gg    = t2 % (NG / 8);
        const int b     = t2 / (NG / 8);
        const int p0    = chunk * PCH;

        if (tid < 8) {
            const float4 gb = reinterpret_cast<const float4*>(gt)[b * NG + gg * 8 + tid];
            float hw = 0.5f * gb.z, hh = 0.5f * gb.w;
            float x0 = gb.x - hw, y0 = gb.y - hh;
            float x1 = gb.x + hw, y1 = gb.y + hh;
            float ga = (x1 - x0) * (y1 - y0);
            opaque(ga);
            a_gx0[tid] = x0; a_gy0[tid] = y0;
            a_gx1[tid] = x1; a_gy1[tid] = y1;
            a_ga[tid]  = ga;
        }
        __syncthreads();

        float        bv[8] = {-1.f,-1.f,-1.f,-1.f,-1.f,-1.f,-1.f,-1.f};
        unsigned int bp[8] = {0,0,0,0,0,0,0,0};

        for (int i = tid; i < PCH; i += 256) {
            const int p = p0 + i;
            if (p >= NP) break;
            const float4 pb = reinterpret_cast<const float4*>(pred)[(size_t)b * NP + p];
            float hw = 0.5f * pb.z, hh = 0.5f * pb.w;
            const float px0 = pb.x - hw, py0 = pb.y - hh;
            const float px1 = pb.x + hw, py1 = pb.y + hh;
            float pa = (px1 - px0) * (py1 - py0);
            opaque(pa);

            #pragma unroll
            for (int j = 0; j < 8; ++j) {
                // identical expression structure to streaming role -> bitwise-equal iou
                float w = fmaxf(fminf(a_gx1[j], px1) - fmaxf(a_gx0[j], px0), 0.0f);
                float h = fmaxf(fminf(a_gy1[j], py1) - fmaxf(a_gy0[j], py0), 0.0f);
                float inter = w * h;
                opaque(inter);                           // numpy op order: (ga+pa)-inter
                float iou = inter / ((a_ga[j] + pa) - inter);  // IEEE div
                if (iou > bv[j]) { bv[j] = iou; bp[j] = (unsigned int)p; }  // static idx
            }
        }

        const int lane = tid & 63;
        const int wv = tid >> 6;
        #pragma unroll
        for (int j = 0; j < 8; ++j) {
            unsigned long long k = 0;
            if (bv[j] >= 0.0f)
                k = ((unsigned long long)__float_as_uint(bv[j]) << 32) |
                    (unsigned long long)(0xFFFFFFFFu - bp[j]);
            #pragma unroll
            for (int s = 1; s < 64; s <<= 1)
                k = umax64(k, __shfl_xor(k, s, 64));
            if (lane == 0) s_part[j][wv] = k;
        }
        __syncthreads();

        if (tid < 8) {
            unsigned long long r = umax64(umax64(s_part[tid][0], s_part[tid][1]),
                                          umax64(s_part[tid][2], s_part[tid][3]));
            part[((size_t)b * NG + (size_t)(gg * 8 + tid)) * NPCH + chunk] = r;
        }
    }
}

// Reduce each row's NPCH partials, store 1.0 at the argmax position. 512 rows.
__global__ __launch_bounds__(256) void pos_fix(
    const unsigned long long* __restrict__ part,
    float* __restrict__ out_pos)
{
    const int row = blockIdx.x * 256 + threadIdx.x;    // b*NG + g
    if (row >= NB * NG) return;
    const unsigned long long* pr = part + (size_t)row * NPCH;
    unsigned long long r = pr[0];
    #pragma unroll
    for (int c = 1; c < NPCH; ++c) r = umax64(r, pr[c]);
    unsigned int idx = 0xFFFFFFFFu - (unsigned int)(r & 0xFFFFFFFFull);
    if (idx < NP) out_pos[(size_t)row * NP + idx] = 1.0f;
}

// Fallback (ws too small): re-scan the iou matrix for argmax.
__global__ __launch_bounds__(256) void argmax_scan(
    const float* __restrict__ out_iou,
    float* __restrict__ out_pos)
{
    const int row = blockIdx.x;
    const float4* r4 = reinterpret_cast<const float4*>(out_iou + (size_t)row * NP);

    float bv = -1.0f;
    int   bi = 0x7fffffff;
    for (int c = threadIdx.x; c < NP / 4; c += 256) {
        float4 v = r4[c];
        int p = 4 * c;
        if (v.x > bv) { bv = v.x; bi = p; }
        if (v.y > bv) { bv = v.y; bi = p + 1; }
        if (v.z > bv) { bv = v.z; bi = p + 2; }
        if (v.w > bv) { bv = v.w; bi = p + 3; }
    }
    #pragma unroll
    for (int s = 1; s < 64; s <<= 1) {
        float ov = __shfl_xor(bv, s, 64);
        int   oi = __shfl_xor(bi, s, 64);
        if (ov > bv || (ov == bv && oi < bi)) { bv = ov; bi = oi; }
    }
    __shared__ float sv[4];
    __shared__ int   si[4];
    const int wid = threadIdx.x >> 6;
    if ((threadIdx.x & 63) == 0) { sv[wid] = bv; si[wid] = bi; }
    __syncthreads();
    if (threadIdx.x == 0) {
        for (int w = 1; w < 4; ++w)
            if (sv[w] > bv || (sv[w] == bv && si[w] < bi)) { bv = sv[w]; bi = si[w]; }
        out_pos[(size_t)row * NP + bi] = 1.0f;
    }
}

extern "C" void kernel_launch(void* const* d_in, const int* in_sizes, int n_in,
                              void* d_out, int out_size, void* d_ws, size_t ws_size,
                              hipStream_t stream) {
    const float* pred = (const float*)d_in[0];
    const float* gt   = (const float*)d_in[1];
    float* out_iou = (float*)d_out;
    float* out_pos = out_iou + (size_t)NB * NG * NP;
    float* out_neg = out_pos + (size_t)NB * NG * NP;

    const size_t part_bytes = (size_t)NB * NG * NPCH * sizeof(unsigned long long); // 128 KB

    if (ws_size >= part_bytes) {
        unsigned long long* part = (unsigned long long*)d_ws;
        fused_main<true><<<dim3(NSTREAM + NAMAX), dim3(256), 0, stream>>>(
            pred, gt, out_iou, out_pos, out_neg, part);
        pos_fix<<<dim3((NB * NG + 255) / 256), dim3(256), 0, stream>>>(part, out_pos);
    } else {
        fused_main<false><<<dim3(NSTREAM), dim3(256), 0, stream>>>(
            pred, gt, out_iou, out_pos, out_neg, nullptr);
        argmax_scan<<<dim3(NB * NG), dim3(256), 0, stream>>>(out_iou, out_pos);
    }
}